// Round 20
// baseline (69.209 us; speedup 1.0000x reference)
//
#include <hip/hip_runtime.h>
#include <hip/hip_fp16.h>

#define D_  160
#define H_  192
#define W_  224
#define HW_ (H_ * W_)           // 43008
#define HW2_ (HW_ / 2)          // 21504
#define N_  (D_ * H_ * W_)      // 6881280
#define INV729 (1.0f / 729.0f)
#define HSEG 16
#define NSEG (H_ / HSEG)        // 12
#define NROW (HSEG + 9)         // 25 rows pushed per strip
#define UPD  (NSEG * 2)         // strip-units per d = 24 (2 halves x 12 strips)
#define DBLK (84 * 8)           // k_passD grid size (for ticket finalize)

// Intermediate: bufA = uint4 per 2 points (c0..c3 pt0, c0..c3 pt1, fp16)
//               bufB = dword per 2 points (c4 pt0, c4 pt1, fp16)

__device__ __forceinline__ unsigned pack2(float a, float b) {
    const __half2 h = __floats2half2_rn(a, b);
    return *(const unsigned*)&h;
}

// ---------------------------------------------------------------------------
// Fused W+H box-sum — DUAL d-STREAM per wave (R18 base). Stream A: fp32 ring
// (no pack/unpack on the critical chain); stream B: fp16-packed ring
// (exact-cancel). Interleaved-LDS staging, 3-deep prefetch.
__global__ __launch_bounds__(64) void k_passWH(const float* __restrict__ pred,
                                               const float* __restrict__ targ,
                                               uint4* __restrict__ outA,      // [N/2]
                                               unsigned* __restrict__ outB,   // [N/2]
                                               double* __restrict__ acc,
                                               unsigned* __restrict__ ticket) {
    __shared__ __attribute__((aligned(16))) float2 lds[2][2][128]; // [stream][buf][entry]
    if (blockIdx.x == 0 && threadIdx.x == 0) { *acc = 0.0; *ticket = 0u; } // before k_passD

    const int lane = threadIdx.x;            // one wave per block
    const int unit = blockIdx.x;             // 0 .. 80*UPD-1
    const int dp   = unit / UPD;             // 0..79
    const int rem  = unit % UPD;
    const int half = rem & 1;
    const int h0   = (rem >> 1) * HSEG;
    const long dbaseA = (long)dp * HW_;
    const long dbaseB = (long)(dp + 80) * HW_;
    const int wbase = half * 112;

    // staging roles: lanes 0-29 stage stream A, lanes 30-59 stage stream B.
    const int  sj   = (lane < 30) ? lane : lane - 30;   // chunk 0..29
    const int  w0c  = wbase - 4 + 4 * sj;
    const bool cokG = (lane < 60) && (w0c >= 0) && (w0c + 3 < W_);
    const int  wsc  = w0c < 0 ? 0 : (w0c > W_ - 4 ? W_ - 4 : w0c);
    const long sdb  = (lane < 30) ? dbaseA : dbaseB;
    const int  sstr = (lane < 30) ? 0 : 1;
    const float* gI = targ + sdb + wsc;      // Ii = target
    const float* gJ = pred + sdb + wsc;      // Ji = pred

    // stream A: fp32 ring; stream B: fp16-packed ring
    float2 qA[5][9];
    unsigned qB[5][9];
    #pragma unroll
    for (int c = 0; c < 5; ++c)
        #pragma unroll
        for (int k = 0; k < 9; ++k) { qA[c][k] = make_float2(0.f, 0.f); qB[c][k] = 0u; }
    float SA0[5] = {0,0,0,0,0}, SA1[5] = {0,0,0,0,0};
    float SB0[5] = {0,0,0,0,0}, SB1[5] = {0,0,0,0,0};

    float4 pI[3], pJ[3];                     // 3-deep prefetch (own stream)
    auto fetch = [&](int r, float4& fi, float4& fj) {
        if (r >= NROW) { fi = make_float4(0.f,0.f,0.f,0.f); fj = fi; return; }
        const int hh = h0 - 5 + r;
        const int hc = hh < 0 ? 0 : (hh >= H_ ? H_ - 1 : hh);
        float4 a = *(const float4*)(gI + (long)hc * W_);
        float4 b = *(const float4*)(gJ + (long)hc * W_);
        if (!(cokG && hh >= 0 && hh < H_)) {
            a = make_float4(0.f, 0.f, 0.f, 0.f); b = a;
        }
        fi = a; fj = b;
    };
    auto wr = [&](int row, int slot) {       // interleaved {I,J} entries
        float2* dst = &lds[sstr][row & 1][4 * sj];
        *(float4*)(dst)     = make_float4(pI[slot].x, pJ[slot].x, pI[slot].y, pJ[slot].y);
        *(float4*)(dst + 2) = make_float4(pI[slot].z, pJ[slot].z, pI[slot].w, pJ[slot].w);
    };

    if (lane < 60) {                         // prologue: rows 0..2 in flight
        fetch(0, pI[0], pJ[0]);
        fetch(1, pI[1], pJ[1]);
        fetch(2, pI[2], pJ[2]);
        wr(0, 0);
        fetch(3, pI[0], pJ[0]);
    }

    #pragma unroll
    for (int p = 0; p < NROW; ++p) {
        if (lane < 60) {                     // write row p+1, keep 3 in flight
            wr(p + 1, (p + 1) % 3);
            fetch(p + 4, pI[(p + 1) % 3], pJ[(p + 1) % 3]);
        }
        // hazard: reads of buf[p&1] below precede the next write to buf[p&1]
        // (row p+2, at step p+1) in program order; DS is FIFO per wave.

        if (lane < 56) {
            const int ph = p % 9;            // compile-time (full unroll)

            // ---- window sums, shared helper (per stream) ----
            #define WINDOW(s, w0s, w1s)                                          \
            {   float x[10], y[10];                                              \
                _Pragma("unroll")                                                \
                for (int m = 0; m < 5; ++m) {                                    \
                    const float4 v = *(const float4*)&lds[s][p & 1][2*lane+2*m]; \
                    x[2*m] = v.x; y[2*m] = v.y; x[2*m+1] = v.z; y[2*m+1] = v.w;  \
                }                                                                \
                float sI=0.f, sJ=0.f, sII=0.f, sJJ=0.f, sIJ=0.f;                 \
                _Pragma("unroll")                                                \
                for (int kk = 0; kk < 9; ++kk) {                                 \
                    sI += x[kk]; sJ += y[kk];                                    \
                    sII = fmaf(x[kk], x[kk], sII);                               \
                    sJJ = fmaf(y[kk], y[kk], sJJ);                               \
                    sIJ = fmaf(x[kk], y[kk], sIJ);                               \
                }                                                                \
                w0s[0]=sI;  w1s[0]=sI  + x[9]-x[0];                              \
                w0s[1]=sJ;  w1s[1]=sJ  + y[9]-y[0];                              \
                w0s[2]=sII; w1s[2]=sII + x[9]*x[9]-x[0]*x[0];                    \
                w0s[3]=sJJ; w1s[3]=sJJ + y[9]*y[9]-y[0]*y[0];                    \
                w0s[4]=sIJ; w1s[4]=sIJ + x[9]*y[9]-x[0]*y[0]; }

            // ---- stream A: fp32 ring ----
            {
                float w0s[5], w1s[5];
                WINDOW(0, w0s, w1s)
                #pragma unroll
                for (int c = 0; c < 5; ++c) {
                    SA0[c] += w0s[c] - qA[c][ph].x;
                    SA1[c] += w1s[c] - qA[c][ph].y;
                    qA[c][ph].x = w0s[c];
                    qA[c][ph].y = w1s[c];
                }
                if (p >= 9) {
                    const long rb = dbaseA + (long)(h0 + p - 9) * W_;  // even
                    uint4 oA;
                    oA.x = pack2(SA0[0], SA0[1]); oA.y = pack2(SA0[2], SA0[3]);
                    oA.z = pack2(SA1[0], SA1[1]); oA.w = pack2(SA1[2], SA1[3]);
                    outA[rb / 2 + half * 56 + lane] = oA;
                    outB[rb / 2 + half * 56 + lane] = pack2(SA0[4], SA1[4]);
                }
            }
            // ---- stream B: fp16-packed ring (exact cancel) ----
            {
                float w0s[5], w1s[5];
                WINDOW(1, w0s, w1s)
                #pragma unroll
                for (int c = 0; c < 5; ++c) {
                    const unsigned nq = pack2(w0s[c], w1s[c]);
                    const float2 nf = __half22float2(*(const __half2*)&nq);
                    const float2 of = __half22float2(*(const __half2*)&qB[c][ph]);
                    SB0[c] += nf.x - of.x;
                    SB1[c] += nf.y - of.y;
                    qB[c][ph] = nq;
                }
                if (p >= 9) {
                    const long rb = dbaseB + (long)(h0 + p - 9) * W_;  // even
                    uint4 oA;
                    oA.x = pack2(SB0[0], SB0[1]); oA.y = pack2(SB0[2], SB0[3]);
                    oA.z = pack2(SB1[0], SB1[1]); oA.w = pack2(SB1[2], SB1[3]);
                    outA[rb / 2 + half * 56 + lane] = oA;
                    outB[rb / 2 + half * 56 + lane] = pack2(SB0[4], SB1[4]);
                }
            }
            #undef WINDOW
        }
    }
}

// ---------------------------------------------------------------------------
// D-axis 9-tap sliding sum + cc + reduction + FUSED FINALIZE (last block
// writes -sum/N to out via device-scope ticket). TWO points per thread.
__global__ __launch_bounds__(256) void k_passD(const uint4* __restrict__ bufA,
                                               const unsigned* __restrict__ bufB,
                                               double* __restrict__ acc,
                                               unsigned* __restrict__ ticket,
                                               float* __restrict__ out) {
    const int DSEG = D_ / 8;                // 20
    const int p2 = blockIdx.x * blockDim.x + threadIdx.x;   // < HW2_
    const int d0 = blockIdx.y * DSEG;

    float2 q[5][9], S[5];                   // .x = pt0, .y = pt1
    #pragma unroll
    for (int c = 0; c < 5; ++c) S[c] = make_float2(0.f, 0.f);

    #pragma unroll
    for (int k = 0; k < 9; ++k) {
        const int dd = d0 - 5 + k;          // d0+3 <= 143 < 160
        uint4 va = make_uint4(0u, 0u, 0u, 0u);
        unsigned vb = 0u;
        if (dd >= 0) {
            va = bufA[(long)dd * HW2_ + p2];
            vb = bufB[(long)dd * HW2_ + p2];
        }
        const float2 a01 = __half22float2(*(const __half2*)&va.x);
        const float2 a23 = __half22float2(*(const __half2*)&va.y);
        const float2 b01 = __half22float2(*(const __half2*)&va.z);
        const float2 b23 = __half22float2(*(const __half2*)&va.w);
        const float2 c44 = __half22float2(*(const __half2*)&vb);
        q[0][k] = make_float2(a01.x, b01.x); S[0].x += a01.x; S[0].y += b01.x;
        q[1][k] = make_float2(a01.y, b01.y); S[1].x += a01.y; S[1].y += b01.y;
        q[2][k] = make_float2(a23.x, b23.x); S[2].x += a23.x; S[2].y += b23.x;
        q[3][k] = make_float2(a23.y, b23.y); S[3].x += a23.y; S[3].y += b23.y;
        q[4][k] = make_float2(c44.x, c44.y); S[4].x += c44.x; S[4].y += c44.y;
    }

    float myacc = 0.f;
    #pragma unroll
    for (int j = 0; j < DSEG; ++j) {        // output d = d0+j
        const int dd = d0 + 4 + j;
        uint4 va = make_uint4(0u, 0u, 0u, 0u);
        unsigned vb = 0u;
        if (dd < D_) {
            va = bufA[(long)dd * HW2_ + p2];
            vb = bufB[(long)dd * HW2_ + p2];
        }
        const float2 a01 = __half22float2(*(const __half2*)&va.x);
        const float2 a23 = __half22float2(*(const __half2*)&va.y);
        const float2 b01 = __half22float2(*(const __half2*)&va.z);
        const float2 b23 = __half22float2(*(const __half2*)&va.w);
        const float2 c44 = __half22float2(*(const __half2*)&vb);
        const float2 nv[5] = {
            make_float2(a01.x, b01.x), make_float2(a01.y, b01.y),
            make_float2(a23.x, b23.x), make_float2(a23.y, b23.y),
            make_float2(c44.x, c44.y)
        };
        const int ph = j % 9;               // compile-time
        #pragma unroll
        for (int c = 0; c < 5; ++c) {
            S[c].x += nv[c].x - q[c][ph].x;
            S[c].y += nv[c].y - q[c][ph].y;
            q[c][ph] = nv[c];
        }
        #pragma unroll
        for (int e = 0; e < 2; ++e) {
            const float mu1 = (e ? S[0].y : S[0].x) * INV729;
            const float mu2 = (e ? S[1].y : S[1].x) * INV729;
            const float s1  = (e ? S[2].y : S[2].x) * INV729 - mu1 * mu1;
            const float s2  = (e ? S[3].y : S[3].x) * INV729 - mu2 * mu2;
            const float s12 = (e ? S[4].y : S[4].x) * INV729 - mu1 * mu2;
            const float den = fmaxf(s1 * s2, 1.1920929e-7f);  // finfo(f32).eps
            myacc += (s12 * s12) / den;
        }
    }

    __shared__ float red[256];
    red[threadIdx.x] = myacc;
    __syncthreads();
    #pragma unroll
    for (int s = 128; s > 0; s >>= 1) {
        if (threadIdx.x < s) red[threadIdx.x] += red[threadIdx.x + s];
        __syncthreads();
    }
    if (threadIdx.x == 0) {
        const double prior = atomicAdd(acc, (double)red[0]);
        __threadfence();                     // acc-add visible before ticket-add
        const unsigned old = atomicAdd(ticket, 1u);
        if (old == DBLK - 1) {               // all other acc-adds fence-ordered
            const double total = prior + (double)red[0];
            out[0] = (float)(-total / (double)N_);
        }
    }
}

// ---------------------------------------------------------------------------
extern "C" void kernel_launch(void* const* d_in, const int* in_sizes, int n_in,
                              void* d_out, int out_size, void* d_ws, size_t ws_size,
                              hipStream_t stream) {
    const float* pred = (const float*)d_in[0];
    const float* targ = (const float*)d_in[1];

    uint4*    bufA   = (uint4*)d_ws;                               // N/2 x 16B
    unsigned* bufB   = (unsigned*)((char*)d_ws + (size_t)(N_ / 2) * 16);
    double*   acc    = (double*)((char*)d_ws + (size_t)(N_ / 2) * 16 + (size_t)(N_ / 2) * 4);
    unsigned* ticket = (unsigned*)(acc + 1);
    float*    out    = (float*)d_out;

    // 1920 dual-units (80 d-pairs x 24 strip-units), 1 wave/block
    k_passWH<<<80 * UPD, 64, 0, stream>>>(pred, targ, bufA, bufB, acc, ticket);
    dim3 g3(HW2_ / 256, 8);     // 84 x 8 = 672 blocks
    k_passD<<<g3, 256, 0, stream>>>(bufA, bufB, acc, ticket, out);
}

// Round 21
// 55.396 us; speedup vs baseline: 1.2493x; 1.2493x over previous
//
#include <hip/hip_runtime.h>
#include <hip/hip_fp16.h>

#define D_  160
#define H_  192
#define W_  224
#define HW_ (H_ * W_)           // 43008
#define HW2_ (HW_ / 2)          // 21504
#define N_  (D_ * H_ * W_)      // 6881280
#define INV729 (1.0f / 729.0f)
#define HSEG 16
#define NSEG (H_ / HSEG)        // 12
#define NROW (HSEG + 9)         // 25 rows pushed per strip
#define UPD  (NSEG * 2)         // strip-units per d = 24 (2 halves x 12 strips)

// Intermediate: bufA = uint4 per 2 points (c0..c3 pt0, c0..c3 pt1, fp16)
//               bufB = dword per 2 points (c4 pt0, c4 pt1, fp16)

__device__ __forceinline__ unsigned pack2(float a, float b) {
    const __half2 h = __floats2half2_rn(a, b);
    return *(const unsigned*)&h;
}

// ---------------------------------------------------------------------------
// Fused W+H box-sum — DUAL d-STREAM per wave (ILP=2, best-measured config,
// = R18 exactly). Streams A (d) and B (d+80) interleaved; independent ring
// chains overlap each other's memory latency. Per stream: interleaved-LDS
// staging (I/J float2 entries, 5 x b128 window reads), fp16-packed H-ring
// (exact-cancel), 3-deep prefetch. No barriers (wave-private LDS, DS FIFO).
__global__ __launch_bounds__(64) void k_passWH(const float* __restrict__ pred,
                                               const float* __restrict__ targ,
                                               uint4* __restrict__ outA,      // [N/2]
                                               unsigned* __restrict__ outB,   // [N/2]
                                               double* __restrict__ acc) {
    __shared__ __attribute__((aligned(16))) float2 lds[2][2][128]; // [stream][buf][entry]
    if (blockIdx.x == 0 && threadIdx.x == 0) *acc = 0.0;  // before k_passD (stream order)

    const int lane = threadIdx.x;            // one wave per block
    const int unit = blockIdx.x;             // 0 .. 80*UPD-1
    const int dp   = unit / UPD;             // 0..79
    const int rem  = unit % UPD;
    const int half = rem & 1;
    const int h0   = (rem >> 1) * HSEG;
    const long dbaseA = (long)dp * HW_;
    const long dbaseB = (long)(dp + 80) * HW_;
    const int wbase = half * 112;

    // staging roles: lanes 0-29 stage stream A, lanes 30-59 stage stream B.
    const int  sj   = (lane < 30) ? lane : lane - 30;   // chunk 0..29
    const int  w0c  = wbase - 4 + 4 * sj;
    const bool cokG = (lane < 60) && (w0c >= 0) && (w0c + 3 < W_);
    const int  wsc  = w0c < 0 ? 0 : (w0c > W_ - 4 ? W_ - 4 : w0c);
    const long sdb  = (lane < 30) ? dbaseA : dbaseB;
    const int  sstr = (lane < 30) ? 0 : 1;
    const float* gI = targ + sdb + wsc;      // Ii = target
    const float* gJ = pred + sdb + wsc;      // Ji = pred

    // fp16 H-rings: q[stream][c][ph] = half2(w-sum pt0, pt1)
    unsigned q[2][5][9];
    #pragma unroll
    for (int s = 0; s < 2; ++s)
        #pragma unroll
        for (int c = 0; c < 5; ++c)
            #pragma unroll
            for (int k = 0; k < 9; ++k) q[s][c][k] = 0u;
    float S0[2][5] = {{0,0,0,0,0},{0,0,0,0,0}};
    float S1[2][5] = {{0,0,0,0,0},{0,0,0,0,0}};

    float4 pI[3], pJ[3];                     // 3-deep prefetch (own stream)
    auto fetch = [&](int r, float4& fi, float4& fj) {
        if (r >= NROW) { fi = make_float4(0.f,0.f,0.f,0.f); fj = fi; return; }
        const int hh = h0 - 5 + r;
        const int hc = hh < 0 ? 0 : (hh >= H_ ? H_ - 1 : hh);
        float4 a = *(const float4*)(gI + (long)hc * W_);
        float4 b = *(const float4*)(gJ + (long)hc * W_);
        if (!(cokG && hh >= 0 && hh < H_)) {
            a = make_float4(0.f, 0.f, 0.f, 0.f); b = a;
        }
        fi = a; fj = b;
    };
    auto wr = [&](int row, int slot) {       // interleaved {I,J} entries
        float2* dst = &lds[sstr][row & 1][4 * sj];
        *(float4*)(dst)     = make_float4(pI[slot].x, pJ[slot].x, pI[slot].y, pJ[slot].y);
        *(float4*)(dst + 2) = make_float4(pI[slot].z, pJ[slot].z, pI[slot].w, pJ[slot].w);
    };

    if (lane < 60) {                         // prologue: rows 0..2 in flight
        fetch(0, pI[0], pJ[0]);
        fetch(1, pI[1], pJ[1]);
        fetch(2, pI[2], pJ[2]);
        wr(0, 0);
        fetch(3, pI[0], pJ[0]);
    }

    #pragma unroll
    for (int p = 0; p < NROW; ++p) {
        if (lane < 60) {                     // write row p+1, keep 3 in flight
            wr(p + 1, (p + 1) % 3);
            fetch(p + 4, pI[(p + 1) % 3], pJ[(p + 1) % 3]);
        }
        // hazard: reads of buf[p&1] below precede the next write to buf[p&1]
        // (row p+2, at step p+1) in program order; DS is FIFO per wave.

        if (lane < 56) {
            const int ph = p % 9;            // compile-time (full unroll)
            #pragma unroll
            for (int s = 0; s < 2; ++s) {    // stream A then B — independent chains
                float x[10], y[10];
                #pragma unroll
                for (int m = 0; m < 5; ++m) {   // 16B-aligned b128: {I,J,I,J}
                    const float4 v = *(const float4*)&lds[s][p & 1][2 * lane + 2 * m];
                    x[2*m] = v.x; y[2*m] = v.y; x[2*m+1] = v.z; y[2*m+1] = v.w;
                }
                float sI = 0.f, sJ = 0.f, sII = 0.f, sJJ = 0.f, sIJ = 0.f;
                #pragma unroll
                for (int kk = 0; kk < 9; ++kk) {
                    sI  += x[kk];          sJ  += y[kk];
                    sII = fmaf(x[kk], x[kk], sII);
                    sJJ = fmaf(y[kk], y[kk], sJJ);
                    sIJ = fmaf(x[kk], y[kk], sIJ);
                }
                float w0s[5], w1s[5];
                w0s[0] = sI;  w1s[0] = sI  + x[9] - x[0];
                w0s[1] = sJ;  w1s[1] = sJ  + y[9] - y[0];
                w0s[2] = sII; w1s[2] = sII + x[9]*x[9] - x[0]*x[0];
                w0s[3] = sJJ; w1s[3] = sJJ + y[9]*y[9] - y[0]*y[0];
                w0s[4] = sIJ; w1s[4] = sIJ + x[9]*y[9] - x[0]*y[0];

                // fp16 ring update: S += unpack(pack(w)) - old (exact cancel)
                #pragma unroll
                for (int c = 0; c < 5; ++c) {
                    const unsigned nq = pack2(w0s[c], w1s[c]);
                    const float2 nf = __half22float2(*(const __half2*)&nq);
                    const float2 of = __half22float2(*(const __half2*)&q[s][c][ph]);
                    S0[s][c] += nf.x - of.x;
                    S1[s][c] += nf.y - of.y;
                    q[s][c][ph] = nq;
                }
                if (p >= 9) {                // emit row h0+p-9 for this stream
                    const long db = s ? dbaseB : dbaseA;
                    const long rb = db + (long)(h0 + p - 9) * W_;  // even
                    uint4 oA;
                    oA.x = pack2(S0[s][0], S0[s][1]); oA.y = pack2(S0[s][2], S0[s][3]);
                    oA.z = pack2(S1[s][0], S1[s][1]); oA.w = pack2(S1[s][2], S1[s][3]);
                    outA[rb / 2 + half * 56 + lane] = oA;
                    outB[rb / 2 + half * 56 + lane] = pack2(S0[s][4], S1[s][4]);
                }
            }
        }
    }
}

// ---------------------------------------------------------------------------
// D-axis 9-tap sliding sum + cc + reduction. TWO points per thread: one b128
// (bufA) + one b32 (bufB) per d-step. Plain per-block atomicAdd, NO fence
// (R20's fused-finalize fence cost +33 us — reverted).
__global__ __launch_bounds__(256) void k_passD(const uint4* __restrict__ bufA,
                                               const unsigned* __restrict__ bufB,
                                               double* __restrict__ acc) {
    const int DSEG = D_ / 8;                // 20
    const int p2 = blockIdx.x * blockDim.x + threadIdx.x;   // < HW2_
    const int d0 = blockIdx.y * DSEG;

    float2 q[5][9], S[5];                   // .x = pt0, .y = pt1
    #pragma unroll
    for (int c = 0; c < 5; ++c) S[c] = make_float2(0.f, 0.f);

    #pragma unroll
    for (int k = 0; k < 9; ++k) {
        const int dd = d0 - 5 + k;          // d0+3 <= 143 < 160
        uint4 va = make_uint4(0u, 0u, 0u, 0u);
        unsigned vb = 0u;
        if (dd >= 0) {
            va = bufA[(long)dd * HW2_ + p2];
            vb = bufB[(long)dd * HW2_ + p2];
        }
        const float2 a01 = __half22float2(*(const __half2*)&va.x);
        const float2 a23 = __half22float2(*(const __half2*)&va.y);
        const float2 b01 = __half22float2(*(const __half2*)&va.z);
        const float2 b23 = __half22float2(*(const __half2*)&va.w);
        const float2 c44 = __half22float2(*(const __half2*)&vb);
        q[0][k] = make_float2(a01.x, b01.x); S[0].x += a01.x; S[0].y += b01.x;
        q[1][k] = make_float2(a01.y, b01.y); S[1].x += a01.y; S[1].y += b01.y;
        q[2][k] = make_float2(a23.x, b23.x); S[2].x += a23.x; S[2].y += b23.x;
        q[3][k] = make_float2(a23.y, b23.y); S[3].x += a23.y; S[3].y += b23.y;
        q[4][k] = make_float2(c44.x, c44.y); S[4].x += c44.x; S[4].y += c44.y;
    }

    float myacc = 0.f;
    #pragma unroll
    for (int j = 0; j < DSEG; ++j) {        // output d = d0+j
        const int dd = d0 + 4 + j;
        uint4 va = make_uint4(0u, 0u, 0u, 0u);
        unsigned vb = 0u;
        if (dd < D_) {
            va = bufA[(long)dd * HW2_ + p2];
            vb = bufB[(long)dd * HW2_ + p2];
        }
        const float2 a01 = __half22float2(*(const __half2*)&va.x);
        const float2 a23 = __half22float2(*(const __half2*)&va.y);
        const float2 b01 = __half22float2(*(const __half2*)&va.z);
        const float2 b23 = __half22float2(*(const __half2*)&va.w);
        const float2 c44 = __half22float2(*(const __half2*)&vb);
        const float2 nv[5] = {
            make_float2(a01.x, b01.x), make_float2(a01.y, b01.y),
            make_float2(a23.x, b23.x), make_float2(a23.y, b23.y),
            make_float2(c44.x, c44.y)
        };
        const int ph = j % 9;               // compile-time
        #pragma unroll
        for (int c = 0; c < 5; ++c) {
            S[c].x += nv[c].x - q[c][ph].x;
            S[c].y += nv[c].y - q[c][ph].y;
            q[c][ph] = nv[c];
        }
        #pragma unroll
        for (int e = 0; e < 2; ++e) {
            const float mu1 = (e ? S[0].y : S[0].x) * INV729;
            const float mu2 = (e ? S[1].y : S[1].x) * INV729;
            const float s1  = (e ? S[2].y : S[2].x) * INV729 - mu1 * mu1;
            const float s2  = (e ? S[3].y : S[3].x) * INV729 - mu2 * mu2;
            const float s12 = (e ? S[4].y : S[4].x) * INV729 - mu1 * mu2;
            const float den = fmaxf(s1 * s2, 1.1920929e-7f);  // finfo(f32).eps
            myacc += (s12 * s12) / den;
        }
    }

    __shared__ float red[256];
    red[threadIdx.x] = myacc;
    __syncthreads();
    #pragma unroll
    for (int s = 128; s > 0; s >>= 1) {
        if (threadIdx.x < s) red[threadIdx.x] += red[threadIdx.x + s];
        __syncthreads();
    }
    if (threadIdx.x == 0) atomicAdd(acc, (double)red[0]);
}

// ---------------------------------------------------------------------------
__global__ void k_fin(const double* __restrict__ acc, float* __restrict__ out) {
    out[0] = (float)(-(*acc) / (double)N_);
}

// ---------------------------------------------------------------------------
extern "C" void kernel_launch(void* const* d_in, const int* in_sizes, int n_in,
                              void* d_out, int out_size, void* d_ws, size_t ws_size,
                              hipStream_t stream) {
    const float* pred = (const float*)d_in[0];
    const float* targ = (const float*)d_in[1];

    uint4*    bufA = (uint4*)d_ws;                                 // N/2 x 16B
    unsigned* bufB = (unsigned*)((char*)d_ws + (size_t)(N_ / 2) * 16);  // N/2 x 4B
    double*   acc  = (double*)((char*)d_ws + (size_t)(N_ / 2) * 16 + (size_t)(N_ / 2) * 4);
    float*    out  = (float*)d_out;

    // 1920 dual-units (80 d-pairs x 24 strip-units), 1 wave/block
    k_passWH<<<80 * UPD, 64, 0, stream>>>(pred, targ, bufA, bufB, acc);
    dim3 g3(HW2_ / 256, 8);     // 84 x 8 = 672 blocks
    k_passD<<<g3, 256, 0, stream>>>(bufA, bufB, acc);
    k_fin<<<1, 1, 0, stream>>>(acc, out);
}